// Round 4
// baseline (70.207 us; speedup 1.0000x reference)
//
#include <hip/hip_runtime.h>
#include <math.h>

// Problem constants (from reference setup_inputs)
#define CDIM 64
#define CR 16
#define TFR 8
#define NBATCH 16      // NT / T
#define NTOT 128       // NT
#define HWPIX 3136     // 56*56
#define HW4 784        // HWPIX / 4

// ---------------------------------------------------------------------------
// Kernel 1: per-(nt, c) spatial mean of x (blocks 0..8191), plus one extra
// block (8192) that computes M = ex_w (64x16) @ sq_w (16x64) -> (64x64).
// ---------------------------------------------------------------------------
__global__ __launch_bounds__(256) void mean_and_M_kernel(
    const float* __restrict__ x,
    const float* __restrict__ sq_w,   // (CR, C) row-major
    const float* __restrict__ ex_w,   // (C, CR) row-major
    float* __restrict__ xbar,         // (NT*C)
    float* __restrict__ M) {          // (C*C)
  const int b = blockIdx.x;
  if (b == NTOT * CDIM) {
    // M[c][cc] = sum_k ex_w[c*CR+k] * sq_w[k*CDIM+cc]
    for (int e = threadIdx.x; e < CDIM * CDIM; e += 256) {
      const int c = e >> 6, cc = e & (CDIM - 1);
      float m = 0.f;
      #pragma unroll
      for (int k = 0; k < CR; ++k) m += ex_w[c * CR + k] * sq_w[k * CDIM + cc];
      M[e] = m;
    }
    return;
  }
  const float4* xp = reinterpret_cast<const float4*>(x + (size_t)b * HWPIX);
  float s = 0.f;
  for (int i = threadIdx.x; i < HW4; i += 256) {
    float4 v = xp[i];
    s += (v.x + v.y) + (v.z + v.w);
  }
  #pragma unroll
  for (int off = 32; off > 0; off >>= 1) s += __shfl_down(s, off, 64);
  __shared__ float wsum[4];
  const int lane = threadIdx.x & 63, wid = threadIdx.x >> 6;
  if (lane == 0) wsum[wid] = s;
  __syncthreads();
  if (threadIdx.x == 0) {
    float tot = (wsum[0] + wsum[1]) + (wsum[2] + wsum[3]);
    xbar[b] = tot * (1.0f / (float)HWPIX);
  }
}

// ---------------------------------------------------------------------------
// Kernel 2: fused main pass, one block per (n, c); NO LDS, NO barriers.
// att is wave-uniform per block:  a[t] = ex_b[c] + sum_cc M[c,cc]*(xbar[n,0,cc]
// - xbar[n,t,cc])  (t=1..6; t=0,7 give 0 since diff rows are exactly zero).
// Each thread issues its first 8 frame loads BEFORE the att math so the
// uniform VALU work hides under load latency; then streams with a manual
// next-tile prefetch.
//   S  = x * (1 + att)
//   Sc = shift-conv_T(S)  (k=3, zero pad)
//   Gc = BN(gate-conv_T(x))   [BN folded into conv weights]
//   out = Sc * sigmoid(Gc)
// ---------------------------------------------------------------------------
__global__ __launch_bounds__(256) void fused_shift_kernel(
    const float* __restrict__ x,
    const float* __restrict__ xbar,
    const float* __restrict__ M,
    const float* __restrict__ ex_b,
    const float* __restrict__ shift_w, const float* __restrict__ shift_b,
    const float* __restrict__ gate_w,  const float* __restrict__ gate_b,
    const float* __restrict__ bn_gamma, const float* __restrict__ bn_beta,
    const float* __restrict__ bn_mean,  const float* __restrict__ bn_var,
    float* __restrict__ out) {
  const int n = blockIdx.x >> 6;         // 0..15
  const int c = blockIdx.x & (CDIM - 1); // 0..63
  const int tid = threadIdx.x;

  const size_t base_nc = ((size_t)(n * TFR) * CDIM + c) * HWPIX;
  const size_t tstride = (size_t)CDIM * HWPIX;  // frame stride in floats

  // ---- issue first tile's loads immediately ----
  int i = tid;
  float4 cur[TFR];
  #pragma unroll
  for (int t = 0; t < TFR; ++t)
    cur[t] = *reinterpret_cast<const float4*>(x + base_nc + (size_t)i * 4 +
                                              (size_t)t * tstride);

  // ---- wave-uniform att computation (overlaps the loads above) ----
  const float a07 = ex_b[c];
  float ap1[TFR];
  {
    const float* Mr = M + c * CDIM;
    const float* xb0 = xbar + (n * TFR) * CDIM;
    float a[TFR];
    a[0] = a07; a[TFR - 1] = a07;
    #pragma unroll
    for (int t = 1; t < TFR - 1; ++t) {
      float s = a07;
      const float* xbt = xb0 + t * CDIM;
      for (int cc = 0; cc < CDIM; ++cc) s += Mr[cc] * (xb0[cc] - xbt[cc]);
      a[t] = s;
    }
    #pragma unroll
    for (int t = 0; t < TFR; ++t) ap1[t] = 1.f + 1.f / (1.f + __expf(-a[t]));
  }

  // per-channel constants (uniform across block)
  const float sw0 = shift_w[c * 3 + 0], sw1 = shift_w[c * 3 + 1],
              sw2 = shift_w[c * 3 + 2], sb = shift_b[c];
  const float inv = bn_gamma[c] * rsqrtf(bn_var[c] + 1e-3f);
  const float g0 = gate_w[c * 3 + 0] * inv, g1 = gate_w[c * 3 + 1] * inv,
              g2 = gate_w[c * 3 + 2] * inv;
  const float gbias = (gate_b[c] - bn_mean[c]) * inv + bn_beta[c];

  const float4 zero4 = make_float4(0.f, 0.f, 0.f, 0.f);

  while (true) {
    const int nx = i + 256;
    const bool has_next = (nx < HW4);
    float4 nxt[TFR];
    if (has_next) {
      #pragma unroll
      for (int t = 0; t < TFR; ++t)
        nxt[t] = *reinterpret_cast<const float4*>(x + base_nc + (size_t)nx * 4 +
                                                  (size_t)t * tstride);
    }

    // process current tile
    float4 Sv[TFR];
    #pragma unroll
    for (int t = 0; t < TFR; ++t) {
      Sv[t].x = cur[t].x * ap1[t];
      Sv[t].y = cur[t].y * ap1[t];
      Sv[t].z = cur[t].z * ap1[t];
      Sv[t].w = cur[t].w * ap1[t];
    }
    const size_t off = base_nc + (size_t)i * 4;
    #pragma unroll
    for (int t = 0; t < TFR; ++t) {
      const float4 Sm = (t > 0) ? Sv[t - 1] : zero4;
      const float4 Sp = (t < TFR - 1) ? Sv[t + 1] : zero4;
      const float4 xm = (t > 0) ? cur[t - 1] : zero4;
      const float4 xp = (t < TFR - 1) ? cur[t + 1] : zero4;
      float4 o;
      {
        const float sc = sb + sw0 * Sm.x + sw1 * Sv[t].x + sw2 * Sp.x;
        const float gc = gbias + g0 * xm.x + g1 * cur[t].x + g2 * xp.x;
        o.x = sc * (1.f / (1.f + __expf(-gc)));
      }
      {
        const float sc = sb + sw0 * Sm.y + sw1 * Sv[t].y + sw2 * Sp.y;
        const float gc = gbias + g0 * xm.y + g1 * cur[t].y + g2 * xp.y;
        o.y = sc * (1.f / (1.f + __expf(-gc)));
      }
      {
        const float sc = sb + sw0 * Sm.z + sw1 * Sv[t].z + sw2 * Sp.z;
        const float gc = gbias + g0 * xm.z + g1 * cur[t].z + g2 * xp.z;
        o.z = sc * (1.f / (1.f + __expf(-gc)));
      }
      {
        const float sc = sb + sw0 * Sm.w + sw1 * Sv[t].w + sw2 * Sp.w;
        const float gc = gbias + g0 * xm.w + g1 * cur[t].w + g2 * xp.w;
        o.w = sc * (1.f / (1.f + __expf(-gc)));
      }
      *reinterpret_cast<float4*>(out + off + (size_t)t * tstride) = o;
    }

    if (!has_next) break;
    i = nx;
    #pragma unroll
    for (int t = 0; t < TFR; ++t) cur[t] = nxt[t];
  }
}

extern "C" void kernel_launch(void* const* d_in, const int* in_sizes, int n_in,
                              void* d_out, int out_size, void* d_ws, size_t ws_size,
                              hipStream_t stream) {
  const float* x        = (const float*)d_in[0];
  const float* shift_w  = (const float*)d_in[1];
  const float* shift_b  = (const float*)d_in[2];
  const float* gate_w   = (const float*)d_in[3];
  const float* gate_b   = (const float*)d_in[4];
  const float* bn_gamma = (const float*)d_in[5];
  const float* bn_beta  = (const float*)d_in[6];
  const float* bn_mean  = (const float*)d_in[7];
  const float* bn_var   = (const float*)d_in[8];
  const float* sq_w     = (const float*)d_in[9];
  // d_in[10] = sq_b  (cancels in temporal diff -> unused)
  const float* ex_w     = (const float*)d_in[11];
  const float* ex_b     = (const float*)d_in[12];
  float* out = (float*)d_out;

  float* xbar = (float*)d_ws;                  // NT*C floats
  float* M    = (float*)d_ws + NTOT * CDIM;    // C*C floats

  mean_and_M_kernel<<<NTOT * CDIM + 1, 256, 0, stream>>>(x, sq_w, ex_w, xbar, M);
  fused_shift_kernel<<<NBATCH * CDIM, 256, 0, stream>>>(
      x, xbar, M, ex_b, shift_w, shift_b, gate_w, gate_b,
      bn_gamma, bn_beta, bn_mean, bn_var, out);
}